// Round 1
// baseline (416.035 us; speedup 1.0000x reference)
//
#include <hip/hip_runtime.h>

#define NSTEP 2047
#define BATCH 4096

#if __has_builtin(__builtin_amdgcn_exp2f)
#define EXP2(x) __builtin_amdgcn_exp2f(x)
#else
#define EXP2(x) exp2f(x)
#endif

#if __has_builtin(__builtin_amdgcn_rcpf)
#define RCP(x) __builtin_amdgcn_rcpf(x)
#else
#define RCP(x) (1.0f / (x))
#endif

__global__ __launch_bounds__(64, 1)
void cstr_kernel(const float* __restrict__ w, const float* __restrict__ Kp,
                 const float* __restrict__ Lp, const float* __restrict__ Mp,
                 const float* __restrict__ Mop, float* __restrict__ out)
{
    const int b = blockIdx.x * blockDim.x + threadIdx.x;

    // Uniform parameters (compiler scalarizes these loads).
    const float K0 = Kp[0], K1 = Kp[1];
    const float m0 = Mp[0], m1 = Mp[1], m2 = Mp[2], m3 = Mp[3];
    const float MoV = Mop[0];
    // Symmetrized quadratic-form coefficients: phi = sum_{i<=j} c_ij rx_i rx_j + m.rx + Mo
    const float c00 = Lp[0];
    const float c01 = Lp[1] + Lp[4];
    const float c02 = Lp[2] + Lp[8];
    const float c03 = Lp[3] + Lp[12];
    const float c11 = Lp[5];
    const float c12 = Lp[6] + Lp[9];
    const float c13 = Lp[7] + Lp[13];
    const float c22 = Lp[10];
    const float c23 = Lp[11] + Lp[14];
    const float c33 = Lp[15];

    const float* row0 = w + (size_t)b * (2 * NSTEP);   // w[b,0,:]
    const float* row1 = row0 + NSTEP;                  // w[b,1,:]

    constexpr float Hc  = 0.01f;
    constexpr float Acf = 1.0f - Hc;          // 0.99
    constexpr float Bcf = -0.5f * Hc * Hc;    // -H^2/2
    constexpr float T2L = 2.8853900817779268f; // 2*log2(e)
    constexpr float L2E = 1.4426950408889634f; // log2(e)
    constexpr float SC1 = 0.5f * Hc;          // H/2
    constexpr float SC2 = Hc * Hc / 3.0f;     // H^2/3
    constexpr float HH  = 0.5f * Hc;

    float x1, x2, xh1, xh2, u;
    float sxx, suu, sd;

    // ---- step t=0: delta forced to 1, xhat = x0 = (1,0), u = K@x0 = K0 ----
    {
        const float w1 = row0[0], w2 = row1[0];
        const float E  = EXP2(T2L);                  // exp(2*1)
        const float t1 = 1.0f - 2.0f * RCP(E + 1.0f); // tanh(1)
        u   = K0;
        // S(x2=0) = H/2 (Taylor exact to O(H^3))
        x1 = Acf * 1.0f + Hc * SC1 + Hc * u + w1;
        x2 = Bcf - Hc * t1 + HH * u + w2;
        xh1 = 1.0f; xh2 = 0.0f;
        sxx = 1.0f;        // x0.x0
        suu = K0 * K0;     // (K.x0)^2
        sd  = 1.0f;        // delta_0 = 1
    }

    auto step = [&](float w1, float w2, bool acc) {
        // ---- fprev = f(xhat_prev, u_prev) ----
        const float Eh1 = EXP2(xh1 * T2L);
        const float th1 = 1.0f - 2.0f * RCP(Eh1 + 1.0f);     // tanh(xh1)
        const float Eh2 = EXP2(xh2 * T2L);
        const float th2 = 1.0f - 2.0f * RCP(Eh2 + 1.0f);     // tanh(xh2)
        const float sh2 = 1.0f - th2 * th2;
        const float Sh2 = th2 + sh2 * (SC1 - SC2 * th2);     // stage-combined tanh
        const float f1 = Acf * xh1 + Hc * Sh2 + Hc * u;
        const float f2 = Acf * xh2 + Bcf - Hc * th1 + HH * u;
        // ---- x-side tanh (independent of the fprev/phi chain) ----
        const float Ex1 = EXP2(x1 * T2L);
        const float tx1 = 1.0f - 2.0f * RCP(Ex1 + 1.0f);
        const float Ex2 = EXP2(x2 * T2L);
        const float tx2 = 1.0f - 2.0f * RCP(Ex2 + 1.0f);
        const float sx2 = 1.0f - tx2 * tx2;
        const float Sx2 = tx2 + sx2 * (SC1 - SC2 * tx2);
        // ---- phi = rx.L.rx + M.rx + Mo with rx = (x1,x2,f1,f2) ----
        const float g1 = m0 + c00 * x1 + c01 * x2 + c02 * f1 + c03 * f2;
        const float g2 = m1 + c11 * x2 + c12 * f1 + c13 * f2;
        const float g3 = m2 + c22 * f1 + c23 * f2;
        const float g4 = m3 + c33 * f2;
        const float phi = MoV + x1 * g1 + x2 * g2 + f1 * g3 + f2 * g4;
        const float delta = RCP(1.0f + EXP2(-phi * L2E));    // sigmoid
        // ---- xhat, u ----
        const float nh1 = f1 + delta * (x1 - f1);
        const float nh2 = f2 + delta * (x2 - f2);
        const float un  = K0 * nh1 + K1 * nh2;
        if (acc) {
            sxx += x1 * x1 + x2 * x2;
            const float us = K0 * x1 + K1 * x2;
            suu += us * us;
            sd  += delta;
        }
        // ---- x update: u enters linearly ----
        const float nx1 = Acf * x1 + Hc * Sx2 + Hc * un + w1;
        const float nx2 = Acf * x2 + Bcf - Hc * tx1 + HH * un + w2;
        x1 = nx1; x2 = nx2; xh1 = nh1; xh2 = nh2; u = un;
    };

    // t = 1 (scalar loads; latency exposed once, negligible)
    step(row0[1], row1[1], true);

    // t = 2 .. 2045 in 511 groups of 4, software-prefetched one group ahead.
    float2 p0 = *(const float2*)(row0 + 2);
    float2 p1 = *(const float2*)(row0 + 4);
    float2 q0 = *(const float2*)(row1 + 2);
    float2 q1 = *(const float2*)(row1 + 4);
    for (int g = 0; g < 511; ++g) {
        const int t  = 2 + 4 * g;
        const int tn = (g < 510) ? (t + 4) : 2;   // clamp last prefetch to a safe addr
        const float2 n0 = *(const float2*)(row0 + tn);
        const float2 n1 = *(const float2*)(row0 + tn + 2);
        const float2 n2 = *(const float2*)(row1 + tn);
        const float2 n3 = *(const float2*)(row1 + tn + 2);
        step(p0.x, q0.x, true);
        step(p0.y, q0.y, true);
        step(p1.x, q1.x, true);
        step(p1.y, q1.y, true);
        p0 = n0; p1 = n1; q0 = n2; q1 = n3;
    }

    // t = 2046: last step, no stage accumulation.
    step(row0[2046], row1[2046], false);

    // final cost: stage + 10 * x_T.x_T   (Q = I, Qf = 10 I, LAM = 1)
    out[b] = sxx + suu + sd + 10.0f * (x1 * x1 + x2 * x2);
}

extern "C" void kernel_launch(void* const* d_in, const int* in_sizes, int n_in,
                              void* d_out, int out_size, void* d_ws, size_t ws_size,
                              hipStream_t stream) {
    const float* w  = (const float*)d_in[0];
    const float* K  = (const float*)d_in[1];
    const float* L  = (const float*)d_in[2];
    const float* M  = (const float*)d_in[3];
    const float* Mo = (const float*)d_in[4];
    float* out = (float*)d_out;
    cstr_kernel<<<dim3(BATCH / 64), dim3(64), 0, stream>>>(w, K, L, M, Mo, out);
}